// Round 13
// baseline (78.626 us; speedup 1.0000x reference)
//
#include <hip/hip_runtime.h>

#define PCNT 128
#define RCdim 256
#define IMG (RCdim*RCdim)
#define PITCH 44        // %4==0 -> b128-aligned rows; origin C0-6 makes strip windows 16B-aligned (R13)
#define TROWS 36        // 32 + 2*ext2
#define TELEMS (TROWS*PITCH)   // 1584 floats
#define NSLOT 360              // float4 slots per plane (10 per row)
#define NTHREADS 256
#define NTHREADS_R 128
#define NTASK6 (34*6)          // hr strip tasks, 6-wide (204 <= 256: single round)

__device__ __forceinline__ float sig_(float x){ return 1.0f/(1.0f+__expf(-x)); }
__device__ __forceinline__ float th_(float x){ float e=__expf(2.0f*x); return 1.0f-2.0f/(e+1.0f); }

// fp32 -> bf16 round-to-nearest-even
__device__ __forceinline__ unsigned short f2bf(float f){
  unsigned u = __float_as_uint(f);
  u = (u + 0x7fffu + ((u >> 16) & 1u)) >> 16;
  return (unsigned short)u;
}

__device__ __forceinline__ void store_bf4(unsigned short* __restrict__ dst, const float v[4]){
  uint2 p;
  p.x = (unsigned)f2bf(v[0]) | ((unsigned)f2bf(v[1]) << 16);
  p.y = (unsigned)f2bf(v[2]) | ((unsigned)f2bf(v[3]) << 16);
  *(uint2*)dst = p;
}

// Stage one 36x40 plane tile (pitch 44), origin (R0-2, C0-6), zero-padded OOB.
// Global float4 loads are 4B-aligned (gc == 2 mod 4): dwordx4 supports this.
// Partial-OOB float4 at image edges (gc==-2 / gc==254) handled by scalar fixups.
// LDS writes: aligned ds_write_b128 (44r + 4q == 0 mod 4).
__device__ __forceinline__ void stage4(const float* __restrict__ src, float* __restrict__ dst,
                                       int R0, int C0, int tid){
#pragma unroll
  for (int j=0;j<2;++j){
    int s = j*NTHREADS + tid;
    if (s < NSLOT){
      int rr = s/10, q = s - rr*10;
      int gr = R0-2+rr, gc = C0-6+4*q;
      float4 v = make_float4(0.f,0.f,0.f,0.f);
      if ((unsigned)gr < 256u){
        const float* row = src + gr*RCdim;
        if ((unsigned)gc < 253u)      v = *(const float4*)(row + gc);
        else if (gc == -2)            { v.z = row[0];   v.w = row[1];   }
        else if (gc == 254)           { v.x = row[254]; v.y = row[255]; }
      }
      *(float4*)(dst + rr*PITCH + 4*q) = v;
    }
  }
}

// 8-col window via 2x ds_read_b128 (col0 mult of 4), rows row0..row0+2
__device__ __forceinline__ void load8q(const float* __restrict__ T, int row0, int col0, float v[3][8]){
#pragma unroll
  for (int dy=0;dy<3;++dy){
    const float4* p = (const float4*)&T[(row0+dy)*PITCH + col0];
    float4 A=p[0], B=p[1];
    v[dy][0]=A.x; v[dy][1]=A.y; v[dy][2]=A.z; v[dy][3]=A.w;
    v[dy][4]=B.x; v[dy][5]=B.y; v[dy][6]=B.z; v[dy][7]=B.w;
  }
}

// 8-col window via 4x ds_read_b64 (col0 even) — used by hr phase
__device__ __forceinline__ void load8(const float* __restrict__ T, int row0, int col0, float v[3][8]){
#pragma unroll
  for (int dy=0;dy<3;++dy){
    const float2* p = (const float2*)&T[(row0+dy)*PITCH + col0];
    float2 a=p[0],b=p[1],c=p[2],d=p[3];
    v[dy][0]=a.x; v[dy][1]=a.y; v[dy][2]=b.x; v[dy][3]=b.y;
    v[dy][4]=c.x; v[dy][5]=c.y; v[dy][6]=d.x; v[dy][7]=d.y;
  }
}

// 3x3 cross-correlation, 1x4 strip; pixel k center col = window_base + OFF+1+k
template<int OFF>
__device__ __forceinline__ void conv_acc(const float v[3][8], const float w9[9], float o[4]){
#pragma unroll
  for (int ky=0; ky<3; ++ky)
#pragma unroll
    for (int kx=0; kx<3; ++kx){
      const float w = w9[ky*3+kx];
#pragma unroll
      for (int k=0;k<4;++k) o[k] = fmaf(w, v[ky][k+kx+OFF], o[k]);
    }
}

// 6 centers from one 8-wide window: center k at window col k+1
__device__ __forceinline__ void conv_acc6(const float v[3][8], const float w9[9], float o[6]){
#pragma unroll
  for (int ky=0; ky<3; ++ky)
#pragma unroll
    for (int kx=0; kx<3; ++kx){
      const float w = w9[ky*3+kx];
#pragma unroll
      for (int k=0;k<6;++k) o[k] = fmaf(w, v[ky][k+kx], o[k]);
    }
}

__device__ __forceinline__ void load_w18(const float* __restrict__ g, float w0[9], float w1[9]){
#pragma unroll
  for (int i=0;i<9;++i){ w0[i]=g[i]; w1[i]=g[9+i]; }
}

// Reset-gate sigmoids for pair (a, a+1): 6-wide strips, 204 tasks, single round.
// Window col0 = 4+6s (even, b64); centers LDS col = col0+1+k = 5+6s+k (global C0-1+6s+k).
// Valid centers: LDS cols 5..38 -> kn = (s==5) ? 4 : 6.
__device__ __forceinline__ void hr_compute6(float (*sm)[TELEMS],
    const float* __restrict__ w_reset, const float* __restrict__ b_reset,
    int a, int tid, float ga[6], float gb[6]){
  if (tid < NTASK6){
    int row = tid/6, s = tid - row*6;
    int rr = row + 1, col0 = 4 + 6*s;
    float wr0[9],wr1[9];
    load_w18(w_reset + a*18, wr0, wr1);
    const float bra = b_reset[a];
    float va[3][8], vb[3][8];
    load8(sm[0], rr-1, col0, va);
    load8(sm[1], rr-1, col0, vb);
    float ra[6] = {bra,bra,bra,bra,bra,bra};
    conv_acc6(va, wr0, ra); conv_acc6(vb, wr1, ra);
    load8(sm[2], rr-1, col0, va);
    load8(sm[3], rr-1, col0, vb);
    load_w18(w_reset + (a+1)*18, wr0, wr1);
    const float brb = b_reset[a+1];
    float rb[6] = {brb,brb,brb,brb,brb,brb};
    conv_acc6(va, wr0, rb); conv_acc6(vb, wr1, rb);
#pragma unroll
    for (int k=0;k<6;++k){ ga[k]=sig_(ra[k]); gb[k]=sig_(rb[k]); }
  }
}

// hr_a -> sm[0] interior, hr_{a+1} -> sm[2] interior (rows 1..34, cols 5..38).
__device__ __forceinline__ void hr_write6(float (*sm)[TELEMS], int tid,
    const float ga[6], const float gb[6]){
  if (tid < NTASK6){
    int row = tid/6, s = tid - row*6;
    int rr = row + 1, col0 = 4 + 6*s;
    const int kn = (s==5) ? 4 : 6;
#pragma unroll
    for (int k=0;k<6;++k){
      if (k < kn){
        int o = rr*PITCH + col0 + 1 + k;
        sm[0][o] = sm[4][o] * ga[k];
        sm[2][o] = sm[5][o] * gb[k];
      }
    }
  }
}

__global__ void init_out(const float* __restrict__ bias, float* __restrict__ out){
  int i = blockIdx.x * NTHREADS + threadIdx.x;
  out[i] = bias[i];
}

// out[px] = bias[px] + sum_p ns[p][px] * w_read[px][p]; ns is bf16, 2 px per thread
__global__ void __launch_bounds__(NTHREADS_R)
reduce_out(const unsigned short* __restrict__ ns, const float* __restrict__ w_read,
           const float* __restrict__ bias, float* __restrict__ out){
  const int px0 = (blockIdx.x*NTHREADS_R + threadIdx.x)*2;
  float acc0 = bias[px0], acc1 = bias[px0+1];
  const float* wr0 = w_read + (size_t)px0*PCNT;
  const float* wr1 = wr0 + PCNT;
#pragma unroll 4
  for (int p0 = 0; p0 < PCNT; p0 += 4){
    const float4 wa = *(const float4*)&wr0[p0];
    const float4 wb = *(const float4*)&wr1[p0];
#pragma unroll
    for (int j=0;j<4;++j){
      unsigned v = *(const unsigned*)&ns[(size_t)(p0+j)*IMG + px0];
      float n0 = __uint_as_float(v << 16);
      float n1 = __uint_as_float(v & 0xffff0000u);
      acc0 = fmaf(n0, (&wa.x)[j], acc0);
      acc1 = fmaf(n1, (&wb.x)[j], acc1);
    }
  }
  out[px0]   = acc0;
  out[px0+1] = acc1;
}

// R12 structure; strip-conv windows now 16B-aligned -> ds_read_b128 (conflict-free),
// staging LDS writes b128. Thread strip centers at LDS cols tcol+6..tcol+9.
template<bool SPLIT>
__global__ void __launch_bounds__(NTHREADS, 4)
gru_fused(const float* __restrict__ x, const float* __restrict__ h,
          const float* __restrict__ w_reset, const float* __restrict__ b_reset,
          const float* __restrict__ w_update, const float* __restrict__ b_update,
          const float* __restrict__ w_out, const float* __restrict__ b_out,
          const float* __restrict__ w_read, unsigned short* __restrict__ wsb,
          float* __restrict__ out)
{
  __shared__ float sm[6][TELEMS];  // 38016 B -> 4 blocks/CU (152 KB)
  const int tid  = threadIdx.x;
  const int bid  = blockIdx.x;
  const int pg   = bid & 15;
  const int tile = bid >> 4;
  const int R0 = (tile >> 3) * 32;
  const int C0 = (tile & 7) * 32;
  const int trow = tid >> 3;
  const int tcol = (tid & 7) * 4;
  const int gidx = (R0 + trow) * RCdim + C0 + tcol;
  const int wc   = tcol + 4;       // strip window base col (0 mod 4 -> b128)

  float acc[4] = {0.f,0.f,0.f,0.f};
  float v0[3][8], v1[3][8];

  // ==== Phase A: a = 4pg+2t -> low a, low a+1, high 64+2pg+t ====
#pragma unroll 1
  for (int t = 0; t < 2; ++t){
    const int a  = 4*pg + 2*t;
    const int ph = 64 + 2*pg + t;
    __syncthreads();
    stage4(x + (size_t)(2*a  )*IMG, sm[0], R0,C0,tid);
    stage4(x + (size_t)(2*a+1)*IMG, sm[1], R0,C0,tid);
    stage4(x + (size_t)(2*a+2)*IMG, sm[2], R0,C0,tid);
    stage4(x + (size_t)(2*a+3)*IMG, sm[3], R0,C0,tid);
    stage4(h + (size_t)(a    )*IMG, sm[4], R0,C0,tid);
    stage4(h + (size_t)(a+1  )*IMG, sm[5], R0,C0,tid);
    __syncthreads();

    float hc0[4], hc1[4], uH[4];
    { // high update conv (h_a, h_{a+1}); capture h centers for lows
      float wa[9], wb[9];
      load_w18(w_update + ph*18, wa, wb);
      const float b = b_update[ph];
      float uo[4] = {b,b,b,b};
      load8q(sm[4], trow+1, wc, v0);
      load8q(sm[5], trow+1, wc, v1);
      conv_acc<1>(v0, wa, uo); conv_acc<1>(v1, wb, uo);
#pragma unroll
      for (int k=0;k<4;++k){ hc0[k]=v0[1][k+2]; hc1[k]=v1[1][k+2]; uH[k]=sig_(uo[k]); }
    }
    { // low plant a
      float wua[9],wub[9],woa[9],wob[9];
      load_w18(w_update + a*18, wua, wub);
      load_w18(w_out    + a*18, woa, wob);
      const float bu=b_update[a], bo=b_out[a];
      float uo[4]={bu,bu,bu,bu}, co[4]={bo,bo,bo,bo};
      load8q(sm[0], trow+1, wc, v0);
      load8q(sm[1], trow+1, wc, v1);
      conv_acc<1>(v0, wua, uo); conv_acc<1>(v1, wub, uo);
      conv_acc<1>(v0, woa, co); conv_acc<1>(v1, wob, co);
      float ns0[4];
#pragma unroll
      for (int k=0;k<4;++k){ float u=sig_(uo[k]); ns0[k]=hc0[k]+u*(th_(co[k])-hc0[k]); }
      if (SPLIT){
        store_bf4(&wsb[(size_t)a*IMG + gidx], ns0);
      } else {
#pragma unroll
        for (int k=0;k<4;++k)
          acc[k] = fmaf(ns0[k], w_read[(size_t)(gidx+k)*PCNT + a], acc[k]);
      }
    }
    { // low plant a+1
      float wua[9],wub[9],woa[9],wob[9];
      load_w18(w_update + (a+1)*18, wua, wub);
      load_w18(w_out    + (a+1)*18, woa, wob);
      const float bu=b_update[a+1], bo=b_out[a+1];
      float uo[4]={bu,bu,bu,bu}, co[4]={bo,bo,bo,bo};
      load8q(sm[2], trow+1, wc, v0);
      load8q(sm[3], trow+1, wc, v1);
      conv_acc<1>(v0, wua, uo); conv_acc<1>(v1, wub, uo);
      conv_acc<1>(v0, woa, co); conv_acc<1>(v1, wob, co);
      float ns1[4];
#pragma unroll
      for (int k=0;k<4;++k){ float u=sig_(uo[k]); ns1[k]=hc1[k]+u*(th_(co[k])-hc1[k]); }
      if (SPLIT){
        store_bf4(&wsb[(size_t)(a+1)*IMG + gidx], ns1);
      } else {
#pragma unroll
        for (int k=0;k<4;++k)
          acc[k] = fmaf(ns1[k], w_read[(size_t)(gidx+k)*PCNT + (a+1)], acc[k]);
      }
    }
    float ga[6], gb[6];
    hr_compute6(sm, w_reset, b_reset, a, tid, ga, gb);
    __syncthreads();
    hr_write6(sm, tid, ga, gb);
    __syncthreads();
    { // high cand conv (hr pair) + blend
      float woa[9], wob[9];
      load_w18(w_out + ph*18, woa, wob);
      const float bo = b_out[ph];
      float co[4]={bo,bo,bo,bo};
      load8q(sm[0], trow+1, wc, v0);
      load8q(sm[2], trow+1, wc, v1);
      conv_acc<1>(v0, woa, co); conv_acc<1>(v1, wob, co);
      const float4 hp4 = *(const float4*)&h[(size_t)ph*IMG + gidx];
      const float hp[4] = {hp4.x,hp4.y,hp4.z,hp4.w};
      float nsH[4];
#pragma unroll
      for (int k=0;k<4;++k) nsH[k] = hp[k] + uH[k]*(th_(co[k])-hp[k]);
      if (SPLIT){
        store_bf4(&wsb[(size_t)ph*IMG + gidx], nsH);
      } else {
#pragma unroll
        for (int k=0;k<4;++k)
          acc[k] = fmaf(nsH[k], w_read[(size_t)(gidx+k)*PCNT + ph], acc[k]);
      }
    }
  }

  // ==== Phase B: a = 64+4pg+2t -> high plant 96+2pg+t ====
#pragma unroll 1
  for (int t = 0; t < 2; ++t){
    const int a    = 64 + 4*pg + 2*t;
    const int ph   = 96 + 2*pg + t;
    const int base = 8*pg + 4*t;
    __syncthreads();
    stage4(h + (size_t)(base  )*IMG, sm[0], R0,C0,tid);
    stage4(h + (size_t)(base+1)*IMG, sm[1], R0,C0,tid);
    stage4(h + (size_t)(base+2)*IMG, sm[2], R0,C0,tid);
    stage4(h + (size_t)(base+3)*IMG, sm[3], R0,C0,tid);
    stage4(h + (size_t)(a     )*IMG, sm[4], R0,C0,tid);
    stage4(h + (size_t)(a+1   )*IMG, sm[5], R0,C0,tid);
    __syncthreads();

    float uH[4];
    {
      float wa[9], wb[9];
      load_w18(w_update + ph*18, wa, wb);
      const float bu = b_update[ph];
      float uo[4] = {bu,bu,bu,bu};
      load8q(sm[4], trow+1, wc, v0);
      load8q(sm[5], trow+1, wc, v1);
      conv_acc<1>(v0, wa, uo); conv_acc<1>(v1, wb, uo);
#pragma unroll
      for (int k=0;k<4;++k) uH[k]=sig_(uo[k]);
    }
    float ga[6], gb[6];
    hr_compute6(sm, w_reset, b_reset, a, tid, ga, gb);
    __syncthreads();
    hr_write6(sm, tid, ga, gb);
    __syncthreads();
    {
      float wa[9], wb[9];
      load_w18(w_out + ph*18, wa, wb);
      const float bo = b_out[ph];
      float co[4] = {bo,bo,bo,bo};
      load8q(sm[0], trow+1, wc, v0);
      load8q(sm[2], trow+1, wc, v1);
      conv_acc<1>(v0, wa, co); conv_acc<1>(v1, wb, co);
      const float4 hp4 = *(const float4*)&h[(size_t)ph*IMG + gidx];
      const float hp[4] = {hp4.x,hp4.y,hp4.z,hp4.w};
      float nsH[4];
#pragma unroll
      for (int k=0;k<4;++k) nsH[k] = hp[k] + uH[k]*(th_(co[k])-hp[k]);
      if (SPLIT){
        store_bf4(&wsb[(size_t)ph*IMG + gidx], nsH);
      } else {
#pragma unroll
        for (int k=0;k<4;++k)
          acc[k] = fmaf(nsH[k], w_read[(size_t)(gidx+k)*PCNT + ph], acc[k]);
      }
    }
  }

  if (!SPLIT){
#pragma unroll
    for (int k=0;k<4;++k) atomicAdd(&out[gidx+k], acc[k]);
  }
}

extern "C" void kernel_launch(void* const* d_in, const int* in_sizes, int n_in,
                              void* d_out, int out_size, void* d_ws, size_t ws_size,
                              hipStream_t stream) {
  const float* x     = (const float*)d_in[0];
  const float* h     = (const float*)d_in[1];
  const float* wrst  = (const float*)d_in[2];
  const float* brst  = (const float*)d_in[3];
  const float* wupd  = (const float*)d_in[4];
  const float* bupd  = (const float*)d_in[5];
  const float* wout  = (const float*)d_in[6];
  const float* bout  = (const float*)d_in[7];
  const float* wread = (const float*)d_in[8];
  const float* bias  = (const float*)d_in[9];
  float* out = (float*)d_out;
  unsigned short* wsb = (unsigned short*)d_ws;

  const bool split = ws_size >= (size_t)PCNT * IMG * sizeof(unsigned short);
  if (split){
    hipLaunchKernelGGL(gru_fused<true>, dim3(64*16), dim3(NTHREADS), 0, stream,
                       x, h, wrst, brst, wupd, bupd, wout, bout, wread, wsb, out);
    hipLaunchKernelGGL(reduce_out, dim3(IMG/(NTHREADS_R*2)), dim3(NTHREADS_R), 0, stream,
                       wsb, wread, bias, out);
  } else {
    hipLaunchKernelGGL(init_out, dim3(IMG/NTHREADS), dim3(NTHREADS), 0, stream, bias, out);
    hipLaunchKernelGGL(gru_fused<false>, dim3(64*16), dim3(NTHREADS), 0, stream,
                       x, h, wrst, brst, wupd, bupd, wout, bout, wread, wsb, out);
  }
}

// Round 14
// 64.011 us; speedup vs baseline: 1.2283x; 1.2283x over previous
//
#include <hip/hip_runtime.h>

#define PCNT 128
#define RCdim 256
#define IMG (RCdim*RCdim)
#define PITCH 42        // mod 4 = 2 -> rows alternate bank class (conflict fix, R5)
#define TROWS 36        // 32 + 2*ext2
#define TELEMS (TROWS*PITCH)   // 1512 floats
#define NSLOT 360              // float4 load slots per plane (10 per row)
#define NTHREADS 256
#define NTHREADS_R 128
#define NTASK6 (34*6)          // hr strip tasks, 6-wide (204 <= 256: single round)

__device__ __forceinline__ float sig_(float x){ return 1.0f/(1.0f+__expf(-x)); }
__device__ __forceinline__ float th_(float x){ float e=__expf(2.0f*x); return 1.0f-2.0f/(e+1.0f); }

// fp32 -> bf16 round-to-nearest-even
__device__ __forceinline__ unsigned short f2bf(float f){
  unsigned u = __float_as_uint(f);
  u = (u + 0x7fffu + ((u >> 16) & 1u)) >> 16;
  return (unsigned short)u;
}

__device__ __forceinline__ void store_bf4(unsigned short* __restrict__ dst, const float v[4]){
  uint2 p;
  p.x = (unsigned)f2bf(v[0]) | ((unsigned)f2bf(v[1]) << 16);
  p.y = (unsigned)f2bf(v[2]) | ((unsigned)f2bf(v[3]) << 16);
  *(uint2*)dst = p;
}

// Stage one 36x40 plane tile (pitch 42), origin (R0-2, C0-4), zero-padded OOB.
__device__ __forceinline__ void stage4(const float* __restrict__ src, float* __restrict__ dst,
                                       int R0, int C0, int tid){
#pragma unroll
  for (int j=0;j<2;++j){
    int s = j*NTHREADS + tid;
    if (s < NSLOT){
      int rr = s/10, q = s - rr*10;
      int gr = R0-2+rr, gc = C0-4+4*q;
      float4 v = make_float4(0.f,0.f,0.f,0.f);
      if ((unsigned)gr < 256u && (unsigned)gc < 253u)
        v = *(const float4*)(src + gr*RCdim + gc);
      float* d = dst + rr*PITCH + 4*q;
      *(float2*)(d  ) = make_float2(v.x, v.y);
      *(float2*)(d+2) = make_float2(v.z, v.w);
    }
  }
}

// 8-col window via 4x ds_read_b64 (col0 even), rows row0..row0+2
__device__ __forceinline__ void load8(const float* __restrict__ T, int row0, int col0, float v[3][8]){
#pragma unroll
  for (int dy=0;dy<3;++dy){
    const float2* p = (const float2*)&T[(row0+dy)*PITCH + col0];
    float2 a=p[0],b=p[1],c=p[2],d=p[3];
    v[dy][0]=a.x; v[dy][1]=a.y; v[dy][2]=b.x; v[dy][3]=b.y;
    v[dy][4]=c.x; v[dy][5]=c.y; v[dy][6]=d.x; v[dy][7]=d.y;
  }
}

// 3x3 cross-correlation, 1x4 strip; pixel k center col = window_base + OFF+1+k
template<int OFF>
__device__ __forceinline__ void conv_acc(const float v[3][8], const float w9[9], float o[4]){
#pragma unroll
  for (int ky=0; ky<3; ++ky)
#pragma unroll
    for (int kx=0; kx<3; ++kx){
      const float w = w9[ky*3+kx];
#pragma unroll
      for (int k=0;k<4;++k) o[k] = fmaf(w, v[ky][k+kx+OFF], o[k]);
    }
}

// 6 centers from one 8-wide window: center k at window col k+1
__device__ __forceinline__ void conv_acc6(const float v[3][8], const float w9[9], float o[6]){
#pragma unroll
  for (int ky=0; ky<3; ++ky)
#pragma unroll
    for (int kx=0; kx<3; ++kx){
      const float w = w9[ky*3+kx];
#pragma unroll
      for (int k=0;k<6;++k) o[k] = fmaf(w, v[ky][k+kx], o[k]);
    }
}

__device__ __forceinline__ void load_w18(const float* __restrict__ g, float w0[9], float w1[9]){
#pragma unroll
  for (int i=0;i<9;++i){ w0[i]=g[i]; w1[i]=g[9+i]; }
}

// Reset-gate sigmoids for pair (a, a+1): 6-wide strips, 204 tasks, single round.
__device__ __forceinline__ void hr_compute6(float (*sm)[TELEMS],
    const float* __restrict__ w_reset, const float* __restrict__ b_reset,
    int a, int tid, float ga[6], float gb[6]){
  if (tid < NTASK6){
    int row = tid/6, s = tid - row*6;
    int rr = row + 1, col0 = 2 + 6*s;
    float wr0[9],wr1[9];
    load_w18(w_reset + a*18, wr0, wr1);
    const float bra = b_reset[a];
    float va[3][8], vb[3][8];
    load8(sm[0], rr-1, col0, va);
    load8(sm[1], rr-1, col0, vb);
    float ra[6] = {bra,bra,bra,bra,bra,bra};
    conv_acc6(va, wr0, ra); conv_acc6(vb, wr1, ra);
    load8(sm[2], rr-1, col0, va);
    load8(sm[3], rr-1, col0, vb);
    load_w18(w_reset + (a+1)*18, wr0, wr1);
    const float brb = b_reset[a+1];
    float rb[6] = {brb,brb,brb,brb,brb,brb};
    conv_acc6(va, wr0, rb); conv_acc6(vb, wr1, rb);
#pragma unroll
    for (int k=0;k<6;++k){ ga[k]=sig_(ra[k]); gb[k]=sig_(rb[k]); }
  }
}

// hr_a -> sm[0] interior, hr_{a+1} -> sm[2] interior (rows 1..34, cols 3..36).
__device__ __forceinline__ void hr_write6(float (*sm)[TELEMS], int tid,
    const float ga[6], const float gb[6]){
  if (tid < NTASK6){
    int row = tid/6, s = tid - row*6;
    int rr = row + 1, col0 = 2 + 6*s;
    const int kn = (s==5) ? 4 : 6;
#pragma unroll
    for (int k=0;k<6;++k){
      if (k < kn){
        int o = rr*PITCH + col0 + 1 + k;
        sm[0][o] = sm[4][o] * ga[k];
        sm[2][o] = sm[5][o] * gb[k];
      }
    }
  }
}

__global__ void init_out(const float* __restrict__ bias, float* __restrict__ out){
  int i = blockIdx.x * NTHREADS + threadIdx.x;
  out[i] = bias[i];
}

// out[px] = bias[px] + sum_p ns[p][px] * w_read[px][p]; ns is bf16, 2 px per thread
__global__ void __launch_bounds__(NTHREADS_R)
reduce_out(const unsigned short* __restrict__ ns, const float* __restrict__ w_read,
           const float* __restrict__ bias, float* __restrict__ out){
  const int px0 = (blockIdx.x*NTHREADS_R + threadIdx.x)*2;
  float acc0 = bias[px0], acc1 = bias[px0+1];
  const float* wr0 = w_read + (size_t)px0*PCNT;
  const float* wr1 = wr0 + PCNT;
#pragma unroll 4
  for (int p0 = 0; p0 < PCNT; p0 += 4){
    const float4 wa = *(const float4*)&wr0[p0];
    const float4 wb = *(const float4*)&wr1[p0];
#pragma unroll
    for (int j=0;j<4;++j){
      unsigned v = *(const unsigned*)&ns[(size_t)(p0+j)*IMG + px0];
      float n0 = __uint_as_float(v << 16);
      float n1 = __uint_as_float(v & 0xffff0000u);
      acc0 = fmaf(n0, (&wa.x)[j], acc0);
      acc1 = fmaf(n1, (&wb.x)[j], acc1);
    }
  }
  out[px0]   = acc0;
  out[px0+1] = acc1;
}

// R10 structure (spill-free at launch_bounds(256,4)); hr phase re-tiled to
// 6-wide strips (204 tasks, single balanced round). Best-known config (R12, 64.0 us).
template<bool SPLIT>
__global__ void __launch_bounds__(NTHREADS, 4)
gru_fused(const float* __restrict__ x, const float* __restrict__ h,
          const float* __restrict__ w_reset, const float* __restrict__ b_reset,
          const float* __restrict__ w_update, const float* __restrict__ b_update,
          const float* __restrict__ w_out, const float* __restrict__ b_out,
          const float* __restrict__ w_read, unsigned short* __restrict__ wsb,
          float* __restrict__ out)
{
  __shared__ float sm[6][TELEMS];  // 36288 B -> 4 blocks/CU
  const int tid  = threadIdx.x;
  const int bid  = blockIdx.x;
  const int pg   = bid & 15;
  const int tile = bid >> 4;
  const int R0 = (tile >> 3) * 32;
  const int C0 = (tile & 7) * 32;
  const int trow = tid >> 3;
  const int tcol = (tid & 7) * 4;
  const int gidx = (R0 + trow) * RCdim + C0 + tcol;

  float acc[4] = {0.f,0.f,0.f,0.f};
  float v0[3][8], v1[3][8];

  // ==== Phase A: a = 4pg+2t -> low a, low a+1, high 64+2pg+t ====
#pragma unroll 1
  for (int t = 0; t < 2; ++t){
    const int a  = 4*pg + 2*t;
    const int ph = 64 + 2*pg + t;
    __syncthreads();
    stage4(x + (size_t)(2*a  )*IMG, sm[0], R0,C0,tid);
    stage4(x + (size_t)(2*a+1)*IMG, sm[1], R0,C0,tid);
    stage4(x + (size_t)(2*a+2)*IMG, sm[2], R0,C0,tid);
    stage4(x + (size_t)(2*a+3)*IMG, sm[3], R0,C0,tid);
    stage4(h + (size_t)(a    )*IMG, sm[4], R0,C0,tid);
    stage4(h + (size_t)(a+1  )*IMG, sm[5], R0,C0,tid);
    __syncthreads();

    float hc0[4], hc1[4], uH[4];
    { // high update conv (h_a, h_{a+1}); capture h centers for lows
      float wa[9], wb[9];
      load_w18(w_update + ph*18, wa, wb);
      const float b = b_update[ph];
      float uo[4] = {b,b,b,b};
      load8(sm[4], trow+1, tcol+2, v0);
      load8(sm[5], trow+1, tcol+2, v1);
      conv_acc<1>(v0, wa, uo); conv_acc<1>(v1, wb, uo);
#pragma unroll
      for (int k=0;k<4;++k){ hc0[k]=v0[1][k+2]; hc1[k]=v1[1][k+2]; uH[k]=sig_(uo[k]); }
    }
    { // low plant a
      float wua[9],wub[9],woa[9],wob[9];
      load_w18(w_update + a*18, wua, wub);
      load_w18(w_out    + a*18, woa, wob);
      const float bu=b_update[a], bo=b_out[a];
      float uo[4]={bu,bu,bu,bu}, co[4]={bo,bo,bo,bo};
      load8(sm[0], trow+1, tcol+2, v0);
      load8(sm[1], trow+1, tcol+2, v1);
      conv_acc<1>(v0, wua, uo); conv_acc<1>(v1, wub, uo);
      conv_acc<1>(v0, woa, co); conv_acc<1>(v1, wob, co);
      float ns0[4];
#pragma unroll
      for (int k=0;k<4;++k){ float u=sig_(uo[k]); ns0[k]=hc0[k]+u*(th_(co[k])-hc0[k]); }
      if (SPLIT){
        store_bf4(&wsb[(size_t)a*IMG + gidx], ns0);
      } else {
#pragma unroll
        for (int k=0;k<4;++k)
          acc[k] = fmaf(ns0[k], w_read[(size_t)(gidx+k)*PCNT + a], acc[k]);
      }
    }
    { // low plant a+1
      float wua[9],wub[9],woa[9],wob[9];
      load_w18(w_update + (a+1)*18, wua, wub);
      load_w18(w_out    + (a+1)*18, woa, wob);
      const float bu=b_update[a+1], bo=b_out[a+1];
      float uo[4]={bu,bu,bu,bu}, co[4]={bo,bo,bo,bo};
      load8(sm[2], trow+1, tcol+2, v0);
      load8(sm[3], trow+1, tcol+2, v1);
      conv_acc<1>(v0, wua, uo); conv_acc<1>(v1, wub, uo);
      conv_acc<1>(v0, woa, co); conv_acc<1>(v1, wob, co);
      float ns1[4];
#pragma unroll
      for (int k=0;k<4;++k){ float u=sig_(uo[k]); ns1[k]=hc1[k]+u*(th_(co[k])-hc1[k]); }
      if (SPLIT){
        store_bf4(&wsb[(size_t)(a+1)*IMG + gidx], ns1);
      } else {
#pragma unroll
        for (int k=0;k<4;++k)
          acc[k] = fmaf(ns1[k], w_read[(size_t)(gidx+k)*PCNT + (a+1)], acc[k]);
      }
    }
    float ga[6], gb[6];
    hr_compute6(sm, w_reset, b_reset, a, tid, ga, gb);
    __syncthreads();
    hr_write6(sm, tid, ga, gb);
    __syncthreads();
    { // high cand conv (hr pair) + blend
      float woa[9], wob[9];
      load_w18(w_out + ph*18, woa, wob);
      const float bo = b_out[ph];
      float co[4]={bo,bo,bo,bo};
      load8(sm[0], trow+1, tcol+2, v0);
      load8(sm[2], trow+1, tcol+2, v1);
      conv_acc<1>(v0, woa, co); conv_acc<1>(v1, wob, co);
      const float4 hp4 = *(const float4*)&h[(size_t)ph*IMG + gidx];
      const float hp[4] = {hp4.x,hp4.y,hp4.z,hp4.w};
      float nsH[4];
#pragma unroll
      for (int k=0;k<4;++k) nsH[k] = hp[k] + uH[k]*(th_(co[k])-hp[k]);
      if (SPLIT){
        store_bf4(&wsb[(size_t)ph*IMG + gidx], nsH);
      } else {
#pragma unroll
        for (int k=0;k<4;++k)
          acc[k] = fmaf(nsH[k], w_read[(size_t)(gidx+k)*PCNT + ph], acc[k]);
      }
    }
  }

  // ==== Phase B: a = 64+4pg+2t -> high plant 96+2pg+t ====
#pragma unroll 1
  for (int t = 0; t < 2; ++t){
    const int a    = 64 + 4*pg + 2*t;
    const int ph   = 96 + 2*pg + t;
    const int base = 8*pg + 4*t;
    __syncthreads();
    stage4(h + (size_t)(base  )*IMG, sm[0], R0,C0,tid);
    stage4(h + (size_t)(base+1)*IMG, sm[1], R0,C0,tid);
    stage4(h + (size_t)(base+2)*IMG, sm[2], R0,C0,tid);
    stage4(h + (size_t)(base+3)*IMG, sm[3], R0,C0,tid);
    stage4(h + (size_t)(a     )*IMG, sm[4], R0,C0,tid);
    stage4(h + (size_t)(a+1   )*IMG, sm[5], R0,C0,tid);
    __syncthreads();

    float uH[4];
    {
      float wa[9], wb[9];
      load_w18(w_update + ph*18, wa, wb);
      const float bu = b_update[ph];
      float uo[4] = {bu,bu,bu,bu};
      load8(sm[4], trow+1, tcol+2, v0);
      load8(sm[5], trow+1, tcol+2, v1);
      conv_acc<1>(v0, wa, uo); conv_acc<1>(v1, wb, uo);
#pragma unroll
      for (int k=0;k<4;++k) uH[k]=sig_(uo[k]);
    }
    float ga[6], gb[6];
    hr_compute6(sm, w_reset, b_reset, a, tid, ga, gb);
    __syncthreads();
    hr_write6(sm, tid, ga, gb);
    __syncthreads();
    {
      float wa[9], wb[9];
      load_w18(w_out + ph*18, wa, wb);
      const float bo = b_out[ph];
      float co[4] = {bo,bo,bo,bo};
      load8(sm[0], trow+1, tcol+2, v0);
      load8(sm[2], trow+1, tcol+2, v1);
      conv_acc<1>(v0, wa, co); conv_acc<1>(v1, wb, co);
      const float4 hp4 = *(const float4*)&h[(size_t)ph*IMG + gidx];
      const float hp[4] = {hp4.x,hp4.y,hp4.z,hp4.w};
      float nsH[4];
#pragma unroll
      for (int k=0;k<4;++k) nsH[k] = hp[k] + uH[k]*(th_(co[k])-hp[k]);
      if (SPLIT){
        store_bf4(&wsb[(size_t)ph*IMG + gidx], nsH);
      } else {
#pragma unroll
        for (int k=0;k<4;++k)
          acc[k] = fmaf(nsH[k], w_read[(size_t)(gidx+k)*PCNT + ph], acc[k]);
      }
    }
  }

  if (!SPLIT){
#pragma unroll
    for (int k=0;k<4;++k) atomicAdd(&out[gidx+k], acc[k]);
  }
}

extern "C" void kernel_launch(void* const* d_in, const int* in_sizes, int n_in,
                              void* d_out, int out_size, void* d_ws, size_t ws_size,
                              hipStream_t stream) {
  const float* x     = (const float*)d_in[0];
  const float* h     = (const float*)d_in[1];
  const float* wrst  = (const float*)d_in[2];
  const float* brst  = (const float*)d_in[3];
  const float* wupd  = (const float*)d_in[4];
  const float* bupd  = (const float*)d_in[5];
  const float* wout  = (const float*)d_in[6];
  const float* bout  = (const float*)d_in[7];
  const float* wread = (const float*)d_in[8];
  const float* bias  = (const float*)d_in[9];
  float* out = (float*)d_out;
  unsigned short* wsb = (unsigned short*)d_ws;

  const bool split = ws_size >= (size_t)PCNT * IMG * sizeof(unsigned short);
  if (split){
    hipLaunchKernelGGL(gru_fused<true>, dim3(64*16), dim3(NTHREADS), 0, stream,
                       x, h, wrst, brst, wupd, bupd, wout, bout, wread, wsb, out);
    hipLaunchKernelGGL(reduce_out, dim3(IMG/(NTHREADS_R*2)), dim3(NTHREADS_R), 0, stream,
                       wsb, wread, bias, out);
  } else {
    hipLaunchKernelGGL(init_out, dim3(IMG/NTHREADS), dim3(NTHREADS), 0, stream, bias, out);
    hipLaunchKernelGGL(gru_fused<false>, dim3(64*16), dim3(NTHREADS), 0, stream,
                       x, h, wrst, brst, wupd, bupd, wout, bout, wread, wsb, out);
  }
}